// Round 1
// 103.373 us; speedup vs baseline: 1.1436x; 1.1436x over previous
//
#include <hip/hip_runtime.h>
#include <math.h>

#define D 16
#define K 16
#define BLK 256

// Workspace layout (float offsets):
//   OFF_A: 8 tiles x 64 lanes x 16 B  = 8 KB   A-frags (f16, MFMA-lane-linear)
//   OFF_T: 8 tiles x 2 halves x 16 f32 = 1 KB  -t' permuted into C-frag reg order
//   OFF_C: 16 f32                                c_k = log(pi_k) - sum(log diag L)
#define OFF_A 0
#define OFF_T 2048
#define OFF_C 2304

typedef _Float16 f16x8 __attribute__((ext_vector_type(8)));
typedef float    f32x16 __attribute__((ext_vector_type(16)));
typedef _Float16 h2 __attribute__((ext_vector_type(2)));

__host__ __device__ constexpr int tri(int i, int j) { return i * (i + 1) / 2 + j; }

static __device__ __forceinline__ unsigned pack2(float f0, float f1) {
    _Float16 h0 = (_Float16)f0, h1 = (_Float16)f1;  // RNE
    unsigned short b0 = __builtin_bit_cast(unsigned short, h0);
    unsigned short b1 = __builtin_bit_cast(unsigned short, h1);
    return ((unsigned)b1 << 16) | (unsigned)b0;
}

// ---------------------------------------------------------------------------
// Prep: one wave; lane k handles cluster k. Changes vs previous version:
//   - single logf (log(pi/prod(l_jj))) instead of 17 logf on the serial chain
//   - triangular inversion uses the Cholesky reciprocals (0 divides, was 120)
//   - emits MFMA-fragment-linear layouts so main reads params as plain
//     coalesced VMEM/LDS loads (no per-k scalar-load serialization)
// ---------------------------------------------------------------------------
__global__ __launch_bounds__(64) void gmm_prep(
    const float* __restrict__ pi, const float* __restrict__ mu,
    const float* __restrict__ Sigma, float* __restrict__ P)
{
    const int k = threadIdx.x;
    if (k >= K) return;

    float M[tri(D - 1, D - 1) + 1];   // 136 packed lower-tri

#pragma unroll
    for (int i = 0; i < D; ++i)
#pragma unroll
        for (int j = 0; j <= i; ++j)
            M[tri(i, j)] = Sigma[k * D * D + i * D + j];

    // Cholesky, packed, in place; keep diag reciprocals + running product.
    float invd[D];
    float prod = 1.f;
#pragma unroll
    for (int j = 0; j < D; ++j) {
        float s = M[tri(j, j)];
#pragma unroll
        for (int p = 0; p < j; ++p) s -= M[tri(j, p)] * M[tri(j, p)];
        float ljj = sqrtf(s);
        prod *= ljj;
        float inv = 1.f / ljj;
        invd[j] = inv;
        M[tri(j, j)] = ljj;
#pragma unroll
        for (int i = j + 1; i < D; ++i) {
            float t = M[tri(i, j)];
#pragma unroll
            for (int p = 0; p < j; ++p) t -= M[tri(i, p)] * M[tri(j, p)];
            M[tri(i, j)] = t * inv;
        }
    }

    // Invert lower-triangular in place (U' = L^-1), divide-free.
#pragma unroll
    for (int j = 0; j < D; ++j) {
        M[tri(j, j)] = invd[j];
#pragma unroll
        for (int i = j + 1; i < D; ++i) {
            float s = 0.f;
#pragma unroll
            for (int p = j; p < i; ++p) s += M[tri(i, p)] * M[tri(p, j)];
            M[tri(i, j)] = -s * invd[i];
        }
    }

    const float invs2 = 0.70710678118654752440f;  // folds the 1/2 of maha

    // t' = U' mu * invs2
    float t[D];
#pragma unroll
    for (int i = 0; i < D; ++i) {
        float acc = 0.f;
#pragma unroll
        for (int j = 0; j <= i; ++j) acc += M[tri(i, j)] * mu[k * D + j];
        t[i] = acc * invs2;
    }

    // c_k: one logf. prod in [1, ~4e7] (eigs >= 1), pi/prod safe in f32.
    P[OFF_C + k] = logf(pi[k] / prod);

    // -t' permuted into 32x32x16 C-frag register order:
    //   C/D layout (guide, m74/m101): col=lane&31, row=(reg&3)+8*(reg>>2)+4*(lane>>5)
    //   tile tt holds clusters 2tt (regs 0..7) and 2tt+1 (regs 8..15).
    const int tt = k >> 1;
    const int hi = (k & 1) * 8;
#pragma unroll
    for (int w = 0; w < 2; ++w)
#pragma unroll
        for (int ii = 0; ii < 8; ++ii) {
            int comp = (ii & 3) + 8 * (ii >> 2) + 4 * w;
            P[OFF_T + tt * 32 + w * 16 + hi + ii] = -t[comp];
        }

    // A-frags, lane-linear: tile tt entry m (=lane): row=m&31, k-elems 8*(m>>5)..+7
    // (A = U' * invs2, lower-triangular, f16). This lane writes the 32 entries
    // whose row belongs to its cluster.
    uint4* PA = (uint4*)(P + OFF_A);
#pragma unroll
    for (int mm = 0; mm < 32; ++mm) {
        int m  = (k & 1) * 16 + (mm & 15) + 32 * (mm >> 4);
        int rr = m & 15;            // row within this cluster's 16x16 block
        int kc = (m >> 5) * 8;      // first feature column of this half
        unsigned dw[4];
#pragma unroll
        for (int e = 0; e < 4; ++e) {
            int c0 = kc + 2 * e, c1 = c0 + 1;
            float f0 = (c0 <= rr) ? M[tri(rr, c0)] * invs2 : 0.f;
            float f1 = (c1 <= rr) ? M[tri(rr, c1)] * invs2 : 0.f;
            dw[e] = pack2(f0, f1);
        }
        PA[tt * 64 + m] = make_uint4(dw[0], dw[1], dw[2], dw[3]);
    }
}

// ---------------------------------------------------------------------------
// Main: one point per thread; each wave batches its 64 points through MFMA.
//   D[256x64] = A[256x16] * B[16x64] + C   (A = all 16 clusters' U'/sqrt2,
//   B = wave's 64 points f16, C = -t' broadcast) -> 16 x mfma_f32_32x32x16_f16
//   per wave replaces 1152 v_dot2 + 848 scalar-dword loads per wave.
//   C/D layout: lane owns col=lane&31 for half w=lane>>5; after the xor-32
//   reduce of the squares, lane l ends up owning point l exactly, so the
//   softmax + float4 stores are unchanged from the previous version.
// ---------------------------------------------------------------------------
__global__ __launch_bounds__(BLK) void gmm_main(
    const float* __restrict__ x, const float* __restrict__ P,
    float* __restrict__ out, int N)
{
    const int tid  = threadIdx.x;
    const int lane = tid & 63;
    const int wave = tid >> 6;
    const int cc   = lane & 31;      // MFMA column (point within half-tile)
    const int w    = lane >> 5;      // lane half
    const long long n = (long long)blockIdx.x * BLK + tid;
    const bool ok = n < (long long)N;

    // 48 B rows (16 banks apart per point -> ~2-way on b128 reads, free)
    __shared__ __align__(16) unsigned short xs[4][64][24];
    __shared__ __align__(64) float ts[256];

    // A-frags: 8 KB, identical for every block -> L1-resident after warmup.
    f16x8 Afr[8];
#pragma unroll
    for (int t = 0; t < 8; ++t)
        Afr[t] = ((const f16x8*)(P + OFF_A))[t * 64 + lane];

    // Stage the C-init table (1 KB) once per block.
    if (tid < 64) ((float4*)ts)[tid] = ((const float4*)(P + OFF_T))[tid];

    // Load my point, cvt to f16, park row in LDS for the wave-level transpose.
    float4 xr0 = {0, 0, 0, 0}, xr1 = xr0, xr2 = xr0, xr3 = xr0;
    if (ok) {
        const float4* p = (const float4*)(x + n * D);
        xr0 = p[0]; xr1 = p[1]; xr2 = p[2]; xr3 = p[3];
    }
    h2 xp[8];
    xp[0] = (h2){(_Float16)xr0.x, (_Float16)xr0.y};
    xp[1] = (h2){(_Float16)xr0.z, (_Float16)xr0.w};
    xp[2] = (h2){(_Float16)xr1.x, (_Float16)xr1.y};
    xp[3] = (h2){(_Float16)xr1.z, (_Float16)xr1.w};
    xp[4] = (h2){(_Float16)xr2.x, (_Float16)xr2.y};
    xp[5] = (h2){(_Float16)xr2.z, (_Float16)xr2.w};
    xp[6] = (h2){(_Float16)xr3.x, (_Float16)xr3.y};
    xp[7] = (h2){(_Float16)xr3.z, (_Float16)xr3.w};

    uint4* rowq = (uint4*)&xs[wave][lane][0];
    rowq[0] = make_uint4(__builtin_bit_cast(unsigned, xp[0]),
                         __builtin_bit_cast(unsigned, xp[1]),
                         __builtin_bit_cast(unsigned, xp[2]),
                         __builtin_bit_cast(unsigned, xp[3]));
    rowq[1] = make_uint4(__builtin_bit_cast(unsigned, xp[4]),
                         __builtin_bit_cast(unsigned, xp[5]),
                         __builtin_bit_cast(unsigned, xp[6]),
                         __builtin_bit_cast(unsigned, xp[7]));

    __syncthreads();

    // B-frags: col = ct*32+cc (point), k-elems = features 8w..8w+7.
    f16x8 Bfr[2];
#pragma unroll
    for (int ct = 0; ct < 2; ++ct)
        Bfr[ct] = *(const f16x8*)(&xs[wave][ct * 32 + cc][w * 8]);

    float r[K];   // maha per cluster for MY point
#pragma unroll
    for (int t = 0; t < 8; ++t) {
        f32x16 ci = *(const f32x16*)(&ts[t * 32 + w * 16]);   // -t', reg order
#pragma unroll
        for (int ct = 0; ct < 2; ++ct) {
            f32x16 a = __builtin_amdgcn_mfma_f32_32x32x16_f16(
                Afr[t], Bfr[ct], ci, 0, 0, 0);
            // squares in f32 (same precision class as the old dot2 path)
            float q0 = fmaf(a[0], a[0], a[1] * a[1]);
            float q1 = fmaf(a[2], a[2], a[3] * a[3]);
            float q2 = fmaf(a[4], a[4], a[5] * a[5]);
            float q3 = fmaf(a[6], a[6], a[7] * a[7]);
            float pA = (q0 + q1) + (q2 + q3);       // cluster 2t, my half
            float q4 = fmaf(a[8],  a[8],  a[9]  * a[9]);
            float q5 = fmaf(a[10], a[10], a[11] * a[11]);
            float q6 = fmaf(a[12], a[12], a[13] * a[13]);
            float q7 = fmaf(a[14], a[14], a[15] * a[15]);
            float pB = (q4 + q5) + (q6 + q7);       // cluster 2t+1, my half
            pA += __shfl_xor(pA, 32);               // join the two halves
            pB += __shfl_xor(pB, 32);
            if (ct == w) { r[2 * t] = pA; r[2 * t + 1] = pB; }  // my point's tile
        }
    }

    // s_k = c_k - maha_k  (c_k uniform -> s_load)
    const float* __restrict__ Pc = P + OFF_C;
#pragma unroll
    for (int kk = 0; kk < K; ++kk) r[kk] = Pc[kk] - r[kk];

    // Register softmax + coalesced float4 stores (lane l owns point l).
    float mx = r[0];
#pragma unroll
    for (int kk = 1; kk < K; ++kk) mx = fmaxf(mx, r[kk]);
    float sum = 0.f;
#pragma unroll
    for (int kk = 0; kk < K; ++kk) {
        float e = __expf(r[kk] - mx);
        r[kk] = e;
        sum += e;
    }
    float inv = 1.f / sum;
    if (ok) {
        float4* po = (float4*)(out + n * D);
        po[0] = (float4){r[0] * inv,  r[1] * inv,  r[2] * inv,  r[3] * inv};
        po[1] = (float4){r[4] * inv,  r[5] * inv,  r[6] * inv,  r[7] * inv};
        po[2] = (float4){r[8] * inv,  r[9] * inv,  r[10] * inv, r[11] * inv};
        po[3] = (float4){r[12] * inv, r[13] * inv, r[14] * inv, r[15] * inv};
    }
}

extern "C" void kernel_launch(void* const* d_in, const int* in_sizes, int n_in,
                              void* d_out, int out_size, void* d_ws, size_t ws_size,
                              hipStream_t stream) {
    const float* x     = (const float*)d_in[0];   // (N, D)
    const float* pi    = (const float*)d_in[1];   // (1, K)
    const float* mu    = (const float*)d_in[2];   // (K, 1, D)
    const float* Sigma = (const float*)d_in[3];   // (K, D, D)
    float* out = (float*)d_out;                   // (N, K)
    const int N = in_sizes[0] / D;

    float* P = (float*)d_ws;                      // 2320 dwords used

    gmm_prep<<<1, 64, 0, stream>>>(pi, mu, Sigma, P);

    const int grid = (N + BLK - 1) / BLK;
    gmm_main<<<grid, BLK, 0, stream>>>(x, P, out, N);
}